// Round 12
// baseline (709.397 us; speedup 1.0000x reference)
//
#include <hip/hip_runtime.h>
#include <math.h>

#define NFFT 1024
#define BLK  512   // 8 waves, ONE batch per block; grid = 128

// ---- DPP cross-lane (VALU pipe), HW-validated R6/R10 ----
// packed ext_vector_type math BANNED (R8/R9). permlane swap builtins verified R10.
template <int CTRL>
__device__ __forceinline__ float dppf(float v) {
    return __int_as_float(__builtin_amdgcn_update_dpp(
        0, __float_as_int(v), CTRL, 0xF, 0xF, true));
}
__device__ __forceinline__ float qx1(float v) { return dppf<0xB1>(v); }   // l^1
__device__ __forceinline__ float qx2(float v) { return dppf<0x4E>(v); }   // l^2
__device__ __forceinline__ float qx3(float v) { return dppf<0x1B>(v); }   // l^3
__device__ __forceinline__ float xr4(float v) { return dppf<0x1B>(dppf<0x141>(v)); } // l^4
__device__ __forceinline__ float xr8(float v) { return dppf<0x128>(v); }  // l^8

__device__ __forceinline__ void pswap16(float v, float& lo, float& hi) {
    auto r = __builtin_amdgcn_permlane16_swap(__float_as_int(v), __float_as_int(v),
                                              false, false);
    lo = __int_as_float(r[0]);
    hi = __int_as_float(r[1]);
}
__device__ __forceinline__ void pswap32(float v, float& lo, float& hi) {
    auto r = __builtin_amdgcn_permlane32_swap(__float_as_int(v), __float_as_int(v),
                                              false, false);
    lo = __int_as_float(r[0]);
    hi = __int_as_float(r[1]);
}

__global__ __launch_bounds__(BLK, 2)
void siva_kernel(const float* __restrict__ x,
                 const float* __restrict__ nu_p,
                 const float* __restrict__ dto_p,
                 const float* __restrict__ cr_p,
                 const int* __restrict__ nt_p,
                 const int* __restrict__ ns_p,
                 float* __restrict__ out) {
    __shared__ float4 bufF[BLK];   // fwd radix-8 gather, A/B interleaved
    __shared__ float4 bufI[BLK];   // inv radix-8 gather

    const int tt = threadIdx.x;    // 0..511
    const int b  = blockIdx.x;
    const int l  = tt & 63;
    const int w  = tt >> 6;        // wave 0..7 = radix-8 slot
    const int R  = (int)(__brev((unsigned)l) >> 26);   // rev6(l)

    const int nT   = nt_p[0];
    const int nsub = ns_p[0];

    const float nu  = (1.0f / (1.0f + expf(-nu_p[0])))  * (0.5f - 0.01f)  + 0.01f;
    const float dto = (1.0f / (1.0f + expf(-dto_p[0]))) * (0.1f - 0.001f) + 0.001f;
    const float cR  = (1.0f / (1.0f + expf(-cr_p[0])))  * (2.0f - 0.5f)   + 0.5f;
    const float dt   = dto / (float)nsub;
    const float dtcR = dt * cR;

    // radix-2 reg-digit twiddle W1024^{tt}
    float2 T10;
    { const float a = (float)tt * (1.0f / 512.0f);
      T10 = make_float2(cospif(a), -sinpif(a)); }

    // Factored fwd gather constants: E8f[j] = W8^{jw} * W512^{lw}
    //  -> z = rotf * [ (a0 + c4w*a1) + w8w*(a2 + c4w*a3) ],  a_i sign-folded by pm
    const float pm = (w & 1) ? -1.0f : 1.0f;                      // (-1)^w
    float2 c4w, w8w, rotf;
    { const float aw = 0.5f * (float)w;                            // W4^w
      c4w = make_float2(cospif(aw), -sinpif(aw));
      const float aw8 = 0.25f * (float)w;                          // W8^w
      w8w = make_float2(cospif(aw8), -sinpif(aw8));
      const float ar = (float)(l * w) * (1.0f / 256.0f);           // W512^{lw}
      rotf = make_float2(cospif(ar), -sinpif(ar)); }

    // Inverse gather coefficients (dense, j=0 skipped at use site).
    float2 D8[8];
    #pragma unroll
    for (int j = 0; j < 8; ++j) {
        const float ai = (float)(w * j) * 0.25f + (float)(l * j) * (1.0f / 256.0f);
        D8[j] = make_float2(cospif(ai), sinpif(ai));
    }

    // Lane-64 radix-2 tables (Round-2 verified machinery).
    float2 wf[6]; float sg[6]; float2 wi[6];
    #pragma unroll
    for (int s = 0; s < 6; ++s) {
        const int h = 32 >> s;
        const int lm = l & (h - 1);
        const bool hif = (l & h) != 0;
        const float a = (float)(lm * (32 / h)) * (1.0f / 32.0f);   // pi units
        wf[s] = hif ? make_float2(cospif(a), -sinpif(a)) : make_float2(1.0f, 0.0f);
        sg[s] = hif ? -1.0f : 1.0f;
        const int h2 = 1 << s;
        const int lm2 = l & (h2 - 1);
        const float a2 = (float)lm2 / (float)h2;
        float2 wb = make_float2(cospif(a2), sinpif(a2));
        if ((l & h2) != 0) { wb.x = -wb.x; wb.y = -wb.y; }
        wi[s] = wb;
    }
    const bool m1 = (l & 1) != 0, m2 = (l & 2) != 0,
               m4 = (l & 4) != 0, m8 = (l & 8) != 0;

    // select-free inverse butterflies for h=4 (s=2), h=8 (s=3)
    float2 cai[2], cbi[2];
    #pragma unroll
    for (int s = 2; s <= 3; ++s) {
        const bool hif = (l & (1 << s)) != 0;
        cai[s - 2] = hif ? wi[s] : make_float2(1.0f, 0.0f);
        cbi[s - 2] = hif ? make_float2(1.0f, 0.0f) : wi[s];
    }

    // Spectral constants. k = 16*rev6(l) + 2*w + p.
    float Sc[2], csn[2], si[2];
    #pragma unroll
    for (int p = 0; p < 2; ++p) {
        const int k = 16 * R + 2 * w + p;
        const float kk = (k <= 512) ? (float)k : (float)(k - 1024);
        const float ka = fabsf(kk);
        const float q  = 1.0f - dtcR * (ka - nu * ka * ka);
        const float a  = (1.0f / q) * (1.0f / 1024.0f);
        const float kkS = (k == 0 || k == 512) ? 0.0f : kk;
        Sc[p]  = a * (1.0f - dt * kkS);
        csn[p] = (k == 0) ? 0.0f : (1.0f / (1024.0f * kk));
        si[p]  = kk * (1.0f / 1024.0f);
    }

    // Fused quad operator Cq = (inv h=2) o (inv h=1) o S o (fwd h=1) o (fwd h=2)
    // (R11-verified). Rows act on quad {l, l^1, l^2, l^3}.
    float2 Cq[2][4];
    {
        auto compose = [&](float2* o, const float2* bb, const float2* aa) {
            #pragma unroll
            for (int e = 0; e < 4; ++e) {
                float cx = 0.0f, cy = 0.0f;
                #pragma unroll
                for (int d = 0; d < 4; ++d) {
                    const float ax = __shfl_xor(aa[d ^ e].x, d);
                    const float ay = __shfl_xor(aa[d ^ e].y, d);
                    cx = fmaf(bb[d].x, ax, fmaf(-bb[d].y, ay, cx));
                    cy = fmaf(bb[d].x, ay, fmaf(bb[d].y, ax, cy));
                }
                o[e] = make_float2(cx, cy);
            }
        };
        const float2 one = make_float2(1.0f, 0.0f);
        const float2 zer = make_float2(0.0f, 0.0f);
        float2 Arow[4] = { make_float2(wf[4].x * sg[4], wf[4].y * sg[4]), zer,
                           wf[4], zer };                                   // fwd h=2
        float2 Brow[4] = { make_float2(sg[5], 0.0f), one, zer, zer };      // fwd h=1
        float2 Erow[4] = { m1 ? wi[0] : one, m1 ? one : wi[0], zer, zer }; // inv h=1
        float2 Frow[4] = { m2 ? wi[1] : one, zer, m2 ? one : wi[1], zer }; // inv h=2
        float2 M1[4], M2[4], M3[4];
        compose(M1, Brow, Arow);
        #pragma unroll
        for (int p = 0; p < 2; ++p) {
            #pragma unroll
            for (int e = 0; e < 4; ++e)
                M2[e] = make_float2(Sc[p] * M1[e].x, Sc[p] * M1[e].y);
            compose(M3, Erow, M2);
            compose(Cq[p], Frow, M3);
        }
    }

    // fwd DIF step: z = wf[s] * (partner + sg[s]*z)
    auto fwd_s = [&](float2& zz, float bx, float by, int s) {
        const float tx = fmaf(sg[s], zz.x, bx);
        const float ty = fmaf(sg[s], zz.y, by);
        zz.x = tx * wf[s].x - ty * wf[s].y;
        zz.y = tx * wf[s].y + ty * wf[s].x;
    };
    // inv DIT step (select form, for init/snapshot paths)
    auto inv_s = [&](float2& zz, float bx, float by, int s, bool hi) {
        const float px = hi ? zz.x : bx, py = hi ? zz.y : by;
        const float qx = hi ? bx : zz.x, qy = hi ? by : zz.y;
        zz.x = qx + px * wi[s].x - py * wi[s].y;
        zz.y = qy + px * wi[s].y + py * wi[s].x;
    };

    // fwd lane chain h=32,16 (permlane) + 8,4 (DPP). h=2,1 handled by caller.
    auto lane_fwd4 = [&](float2 z[2]) {
        #pragma unroll
        for (int r = 0; r < 2; ++r) {
            float lox, hix, loy, hiy;
            pswap32(z[r].x, lox, hix); pswap32(z[r].y, loy, hiy);
            const float tx = fmaf(sg[0], hix, lox);
            const float ty = fmaf(sg[0], hiy, loy);
            z[r].x = tx * wf[0].x - ty * wf[0].y;
            z[r].y = tx * wf[0].y + ty * wf[0].x;
        }
        #pragma unroll
        for (int r = 0; r < 2; ++r) {
            float lox, hix, loy, hiy;
            pswap16(z[r].x, lox, hix); pswap16(z[r].y, loy, hiy);
            const float tx = fmaf(sg[1], hix, lox);
            const float ty = fmaf(sg[1], hiy, loy);
            z[r].x = tx * wf[1].x - ty * wf[1].y;
            z[r].y = tx * wf[1].y + ty * wf[1].x;
        }
        #pragma unroll
        for (int r = 0; r < 2; ++r) fwd_s(z[r], xr8(z[r].x), xr8(z[r].y), 2);
        #pragma unroll
        for (int r = 0; r < 2; ++r) fwd_s(z[r], xr4(z[r].x), xr4(z[r].y), 3);
    };
    // inv lane chain h=4,8 (DPP select-free) + 16,32 (permlane). h=1,2 by caller.
    auto lane_inv4 = [&](float2 z[2]) {
        #pragma unroll
        for (int r = 0; r < 2; ++r) {
            const float px = xr4(z[r].x), py = xr4(z[r].y);
            const float nx = fmaf(cai[0].x, z[r].x, fmaf(-cai[0].y, z[r].y,
                             fmaf(cbi[0].x, px, -cbi[0].y * py)));
            const float ny = fmaf(cai[0].x, z[r].y, fmaf(cai[0].y, z[r].x,
                             fmaf(cbi[0].x, py, cbi[0].y * px)));
            z[r] = make_float2(nx, ny);
        }
        #pragma unroll
        for (int r = 0; r < 2; ++r) {
            const float px = xr8(z[r].x), py = xr8(z[r].y);
            const float nx = fmaf(cai[1].x, z[r].x, fmaf(-cai[1].y, z[r].y,
                             fmaf(cbi[1].x, px, -cbi[1].y * py)));
            const float ny = fmaf(cai[1].x, z[r].y, fmaf(cai[1].y, z[r].x,
                             fmaf(cbi[1].x, py, cbi[1].y * px)));
            z[r] = make_float2(nx, ny);
        }
        #pragma unroll
        for (int r = 0; r < 2; ++r) {
            float lox, hix, loy, hiy;
            pswap16(z[r].x, lox, hix); pswap16(z[r].y, loy, hiy);
            z[r].x = fmaf(wi[4].x, hix, fmaf(-wi[4].y, hiy, lox));
            z[r].y = fmaf(wi[4].x, hiy, fmaf( wi[4].y, hix, loy));
        }
        #pragma unroll
        for (int r = 0; r < 2; ++r) {
            float lox, hix, loy, hiy;
            pswap32(z[r].x, lox, hix); pswap32(z[r].y, loy, hiy);
            z[r].x = fmaf(wi[5].x, hix, fmaf(-wi[5].y, hiy, lox));
            z[r].y = fmaf(wi[5].x, hiy, fmaf( wi[5].y, hix, loy));
        }
    };

    // fused quad stage (fwd h=2,h=1 + S + inv h=1,h=2)
    auto stageQuadC = [&](float2 z[2]) {
        #pragma unroll
        for (int p = 0; p < 2; ++p) {
            const float x1 = qx1(z[p].x), y1 = qx1(z[p].y);
            const float x2 = qx2(z[p].x), y2 = qx2(z[p].y);
            const float x3 = qx3(z[p].x), y3 = qx3(z[p].y);
            float nx = Cq[p][0].x * z[p].x - Cq[p][0].y * z[p].y;
            float ny = Cq[p][0].x * z[p].y + Cq[p][0].y * z[p].x;
            nx = fmaf(Cq[p][1].x, x1, fmaf(-Cq[p][1].y, y1, nx));
            ny = fmaf(Cq[p][1].x, y1, fmaf( Cq[p][1].y, x1, ny));
            nx = fmaf(Cq[p][2].x, x2, fmaf(-Cq[p][2].y, y2, nx));
            ny = fmaf(Cq[p][2].x, y2, fmaf( Cq[p][2].y, x2, ny));
            nx = fmaf(Cq[p][3].x, x3, fmaf(-Cq[p][3].y, y3, nx));
            ny = fmaf(Cq[p][3].x, y3, fmaf( Cq[p][3].y, x3, ny));
            z[p] = make_float2(nx, ny);
        }
    };

    // fwd head: radix-2 reg digit -> LDS write -> factored radix-8 gather
    // (reads interleaved pairwise with the sign-folds to avoid an 8-read DS burst)
    auto fwd_head = [&](float2 z[2]) {
        const float2 A  = make_float2(z[0].x + z[1].x, z[0].y + z[1].y);
        const float2 Dm = make_float2(z[0].x - z[1].x, z[0].y - z[1].y);
        const float2 Bc = make_float2(Dm.x * T10.x - Dm.y * T10.y,
                                      Dm.x * T10.y + Dm.y * T10.x);
        bufF[tt] = make_float4(A.x, A.y, Bc.x, Bc.y);
        __syncthreads();
        // pair (j, j+4): a_i = v[j] + pm*v[j+4]   (A parts .x.y, B parts .z.w)
        float a0x, a0y, a0z, a0w, a1x, a1y, a1z, a1w;
        float a2x, a2y, a2z, a2w, a3x, a3y, a3z, a3w;
        {
            const float4 u0 = bufF[l],        u4 = bufF[256 + l];
            a0x = fmaf(pm, u4.x, u0.x);  a0y = fmaf(pm, u4.y, u0.y);
            a0z = fmaf(pm, u4.z, u0.z);  a0w = fmaf(pm, u4.w, u0.w);
        }
        {
            const float4 u2 = bufF[128 + l],  u6 = bufF[384 + l];
            a1x = fmaf(pm, u6.x, u2.x);  a1y = fmaf(pm, u6.y, u2.y);
            a1z = fmaf(pm, u6.z, u2.z);  a1w = fmaf(pm, u6.w, u2.w);
        }
        {
            const float4 u1 = bufF[64 + l],   u5 = bufF[320 + l];
            a2x = fmaf(pm, u5.x, u1.x);  a2y = fmaf(pm, u5.y, u1.y);
            a2z = fmaf(pm, u5.z, u1.z);  a2w = fmaf(pm, u5.w, u1.w);
        }
        {
            const float4 u3 = bufF[192 + l],  u7 = bufF[448 + l];
            a3x = fmaf(pm, u7.x, u3.x);  a3y = fmaf(pm, u7.y, u3.y);
            a3z = fmaf(pm, u7.z, u3.z);  a3w = fmaf(pm, u7.w, u3.w);
        }
        // A sequence
        {
            const float Ex = fmaf(c4w.x, a1x, fmaf(-c4w.y, a1y, a0x));
            const float Ey = fmaf(c4w.x, a1y, fmaf( c4w.y, a1x, a0y));
            const float Fx = fmaf(c4w.x, a3x, fmaf(-c4w.y, a3y, a2x));
            const float Fy = fmaf(c4w.x, a3y, fmaf( c4w.y, a3x, a2y));
            const float Sx = fmaf(w8w.x, Fx, fmaf(-w8w.y, Fy, Ex));
            const float Sy = fmaf(w8w.x, Fy, fmaf( w8w.y, Fx, Ey));
            z[0] = make_float2(Sx * rotf.x - Sy * rotf.y,
                               Sx * rotf.y + Sy * rotf.x);
        }
        // B sequence
        {
            const float Ex = fmaf(c4w.x, a1z, fmaf(-c4w.y, a1w, a0z));
            const float Ey = fmaf(c4w.x, a1w, fmaf( c4w.y, a1z, a0w));
            const float Fx = fmaf(c4w.x, a3z, fmaf(-c4w.y, a3w, a2z));
            const float Fy = fmaf(c4w.x, a3w, fmaf( c4w.y, a3z, a2w));
            const float Sx = fmaf(w8w.x, Fx, fmaf(-w8w.y, Fy, Ex));
            const float Sy = fmaf(w8w.x, Fy, fmaf( w8w.y, Fx, Ey));
            z[1] = make_float2(Sx * rotf.x - Sy * rotf.y,
                               Sx * rotf.y + Sy * rotf.x);
        }
        lane_fwd4(z);
    };

    // inv tail: lane 4 stages -> LDS write -> dense inverse gather (j=0 skipped,
    // reads interleaved with their FMAs as in R10)
    auto inv_tail = [&](float2 z[2], float& u0o, float& u1o) {
        lane_inv4(z);
        bufI[tt] = make_float4(z[0].x, z[0].y, z[1].x, z[1].y);
        __syncthreads();
        float vAx, vBx, vBy;
        { const float4 v0 = bufI[l];
          vAx = v0.x; vBx = v0.z; vBy = v0.w; }
        #pragma unroll
        for (int j = 1; j < 8; ++j) {
            const float4 v = bufI[64 * j + l];
            vAx = fmaf(D8[j].x, v.x, vAx);  vAx = fmaf(-D8[j].y, v.y, vAx);
            vBx = fmaf(D8[j].x, v.z, vBx);  vBx = fmaf(-D8[j].y, v.w, vBx);
            vBy = fmaf(D8[j].x, v.w, vBy);  vBy = fmaf(D8[j].y, v.z, vBy);
        }
        const float re = vBx * T10.x + vBy * T10.y;   // Re(vB * conj(T10))
        u0o = vAx + re;
        u1o = vAx - re;
    };

    // ---- init: d_to_u (unfused middle) ----
    float2 z[2];
    float u0, u1;
    z[0] = make_float2(x[b * NFFT + tt], 0.0f);
    z[1] = make_float2(x[b * NFFT + tt + 512], 0.0f);
    fwd_head(z);
    #pragma unroll
    for (int r = 0; r < 2; ++r) fwd_s(z[r], qx2(z[r].x), qx2(z[r].y), 4);  // h=2
    #pragma unroll
    for (int r = 0; r < 2; ++r) fwd_s(z[r], qx1(z[r].x), qx1(z[r].y), 5);  // h=1
    #pragma unroll
    for (int p = 0; p < 2; ++p) {
        const float zx = z[p].x, zy = z[p].y;
        z[p] = make_float2(-zy * si[p], zx * si[p]);   // i*k*Z / N
    }
    #pragma unroll
    for (int r = 0; r < 2; ++r) inv_s(z[r], qx1(z[r].x), qx1(z[r].y), 0, m1);
    #pragma unroll
    for (int r = 0; r < 2; ++r) inv_s(z[r], qx2(z[r].x), qx2(z[r].y), 1, m2);
    inv_tail(z, u0, u1);

    for (int ot = 0; ot < nT; ++ot) {
        for (int ss = 0; ss < nsub; ++ss) {
            z[0] = make_float2(u0, 0.5f * u0 * u0);
            z[1] = make_float2(u1, 0.5f * u1 * u1);
            fwd_head(z);
            stageQuadC(z);     // fused: fwd h=2,h=1 + S + inv h=1,h=2
            inv_tail(z, u0, u1);
        }
        // snapshot: u_to_d (unfused middle)
        z[0] = make_float2(u0, 0.0f);
        z[1] = make_float2(u1, 0.0f);
        fwd_head(z);
        #pragma unroll
        for (int r = 0; r < 2; ++r) fwd_s(z[r], qx2(z[r].x), qx2(z[r].y), 4);
        #pragma unroll
        for (int r = 0; r < 2; ++r) fwd_s(z[r], qx1(z[r].x), qx1(z[r].y), 5);
        #pragma unroll
        for (int p = 0; p < 2; ++p) {
            const float zx = z[p].x, zy = z[p].y;
            z[p] = make_float2(zy * csn[p], -zx * csn[p]);  // -i*Z/(N*k)
        }
        #pragma unroll
        for (int r = 0; r < 2; ++r) inv_s(z[r], qx1(z[r].x), qx1(z[r].y), 0, m1);
        #pragma unroll
        for (int r = 0; r < 2; ++r) inv_s(z[r], qx2(z[r].x), qx2(z[r].y), 1, m2);
        float d0, d1;
        inv_tail(z, d0, d1);
        out[(b * NFFT + tt) * nT + ot]       = d0;
        out[(b * NFFT + tt + 512) * nT + ot] = d1;
    }
}

extern "C" void kernel_launch(void* const* d_in, const int* in_sizes, int n_in,
                              void* d_out, int out_size, void* d_ws, size_t ws_size,
                              hipStream_t stream) {
    const float* x     = (const float*)d_in[0];
    const float* nu_p  = (const float*)d_in[1];
    const float* dto_p = (const float*)d_in[2];
    const float* cr_p  = (const float*)d_in[3];
    const int*   nt_p  = (const int*)d_in[4];
    const int*   ns_p  = (const int*)d_in[5];
    float* out = (float*)d_out;

    const int B = in_sizes[0] / NFFT;  // C == 1
    siva_kernel<<<B, BLK, 0, stream>>>(x, nu_p, dto_p, cr_p, nt_p, ns_p, out);
}

// Round 13
// 704.181 us; speedup vs baseline: 1.0074x; 1.0074x over previous
//
#include <hip/hip_runtime.h>
#include <math.h>

#define NFFT 1024
#define BLK  512   // 8 waves, ONE batch per block; grid = 128

// ---- DPP cross-lane (VALU pipe), HW-validated R6/R10 ----
// packed ext_vector_type math BANNED (R8/R9). permlane swap builtins verified R10.
template <int CTRL>
__device__ __forceinline__ float dppf(float v) {
    return __int_as_float(__builtin_amdgcn_update_dpp(
        0, __float_as_int(v), CTRL, 0xF, 0xF, true));
}
__device__ __forceinline__ float qx1(float v) { return dppf<0xB1>(v); }   // l^1
__device__ __forceinline__ float qx2(float v) { return dppf<0x4E>(v); }   // l^2
__device__ __forceinline__ float xr4(float v) { return dppf<0x1B>(dppf<0x141>(v)); } // l^4
__device__ __forceinline__ float xr8(float v) { return dppf<0x128>(v); }  // l^8

__device__ __forceinline__ void pswap16(float v, float& lo, float& hi) {
    auto r = __builtin_amdgcn_permlane16_swap(__float_as_int(v), __float_as_int(v),
                                              false, false);
    lo = __int_as_float(r[0]);
    hi = __int_as_float(r[1]);
}
__device__ __forceinline__ void pswap32(float v, float& lo, float& hi) {
    auto r = __builtin_amdgcn_permlane32_swap(__float_as_int(v), __float_as_int(v),
                                              false, false);
    lo = __int_as_float(r[0]);
    hi = __int_as_float(r[1]);
}

__global__ __launch_bounds__(BLK, 2)
void siva_kernel(const float* __restrict__ x,
                 const float* __restrict__ nu_p,
                 const float* __restrict__ dto_p,
                 const float* __restrict__ cr_p,
                 const int* __restrict__ nt_p,
                 const int* __restrict__ ns_p,
                 float* __restrict__ out) {
    __shared__ float4 bufF[BLK];   // fwd radix-8 gather, A/B interleaved
    __shared__ float4 bufI[BLK];   // inv radix-8 gather

    const int tt = threadIdx.x;    // 0..511
    const int b  = blockIdx.x;
    const int l  = tt & 63;
    const int w  = tt >> 6;        // wave 0..7 = radix-8 slot
    const int R  = (int)(__brev((unsigned)l) >> 26);   // rev6(l)

    const int nT   = nt_p[0];
    const int nsub = ns_p[0];

    const float nu  = (1.0f / (1.0f + expf(-nu_p[0])))  * (0.5f - 0.01f)  + 0.01f;
    const float dto = (1.0f / (1.0f + expf(-dto_p[0]))) * (0.1f - 0.001f) + 0.001f;
    const float cR  = (1.0f / (1.0f + expf(-cr_p[0])))  * (2.0f - 0.5f)   + 0.5f;
    const float dt   = dto / (float)nsub;
    const float dtcR = dt * cR;

    // radix-2 reg-digit twiddle W1024^{tt}
    float2 T10;
    { const float a = (float)tt * (1.0f / 512.0f);
      T10 = make_float2(cospif(a), -sinpif(a)); }

    // Factored fwd gather constants: E8f[j] = W8^{jw} * W512^{lw}
    //  -> z = rotf * [ (a0 + c4w*a1) + w8w*(a2 + c4w*a3) ],  a_i sign-folded by pm
    const float pm = (w & 1) ? -1.0f : 1.0f;                      // (-1)^w
    float2 c4w, w8w, rotf;
    { const float aw = 0.5f * (float)w;                            // W4^w
      c4w = make_float2(cospif(aw), -sinpif(aw));
      const float aw8 = 0.25f * (float)w;                          // W8^w
      w8w = make_float2(cospif(aw8), -sinpif(aw8));
      const float ar = (float)(l * w) * (1.0f / 256.0f);           // W512^{lw}
      rotf = make_float2(cospif(ar), -sinpif(ar)); }

    // Inverse gather coefficients (dense; j=0 skipped at use site).
    float2 D8[8];
    #pragma unroll
    for (int j = 0; j < 8; ++j) {
        const float ai = (float)(w * j) * 0.25f + (float)(l * j) * (1.0f / 256.0f);
        D8[j] = make_float2(cospif(ai), sinpif(ai));
    }

    // Lane-64 radix-2 tables (Round-2 verified machinery).
    float2 wf[6]; float sg[6]; float2 wi[6];
    #pragma unroll
    for (int s = 0; s < 6; ++s) {
        const int h = 32 >> s;
        const int lm = l & (h - 1);
        const bool hif = (l & h) != 0;
        const float a = (float)(lm * (32 / h)) * (1.0f / 32.0f);   // pi units
        wf[s] = hif ? make_float2(cospif(a), -sinpif(a)) : make_float2(1.0f, 0.0f);
        sg[s] = hif ? -1.0f : 1.0f;
        const int h2 = 1 << s;
        const int lm2 = l & (h2 - 1);
        const float a2 = (float)lm2 / (float)h2;
        float2 wb = make_float2(cospif(a2), sinpif(a2));
        if ((l & h2) != 0) { wb.x = -wb.x; wb.y = -wb.y; }
        wi[s] = wb;
    }
    const bool m1 = (l & 1) != 0, m2 = (l & 2) != 0;

    // select-free inverse butterflies for h=2,4,8 (s=1,2,3):
    // z' = cai*own + cbi*partner  (hi lane: own carries wi; lo lane: partner does)
    float2 cai[3], cbi[3];
    #pragma unroll
    for (int s = 1; s <= 3; ++s) {
        const bool hif = (l & (1 << s)) != 0;
        cai[s - 1] = hif ? wi[s] : make_float2(1.0f, 0.0f);
        cbi[s - 1] = hif ? make_float2(1.0f, 0.0f) : wi[s];
    }

    // Spectral constants. k = 16*rev6(l) + 2*w + p.
    float Sc[2], csn[2], si[2];
    #pragma unroll
    for (int p = 0; p < 2; ++p) {
        const int k = 16 * R + 2 * w + p;
        const float kk = (k <= 512) ? (float)k : (float)(k - 1024);
        const float ka = fabsf(kk);
        const float q  = 1.0f - dtcR * (ka - nu * ka * ka);
        const float a  = (1.0f / q) * (1.0f / 1024.0f);
        const float kkS = (k == 0 || k == 512) ? 0.0f : kk;
        Sc[p]  = a * (1.0f - dt * kkS);
        csn[p] = (k == 0) ? 0.0f : (1.0f / (1024.0f * kk));
        si[p]  = kk * (1.0f / 1024.0f);
    }
    // Fused pair operator (fwd h=1 + S + inv h=1): out = A2*z + B2*z^(l^1), real.
    float A2[2], B2[2];
    { const float sg1 = (l & 1) ? -1.0f : 1.0f;
      #pragma unroll
      for (int p = 0; p < 2; ++p) {
          const float so = __shfl_xor(Sc[p], 1);
          A2[p] = Sc[p] + so;
          B2[p] = sg1 * (Sc[p] - so);
      } }

    // fwd DIF step: z = wf[s] * (partner + sg[s]*z)
    auto fwd_s = [&](float2& zz, float bx, float by, int s) {
        const float tx = fmaf(sg[s], zz.x, bx);
        const float ty = fmaf(sg[s], zz.y, by);
        zz.x = tx * wf[s].x - ty * wf[s].y;
        zz.y = tx * wf[s].y + ty * wf[s].x;
    };
    // inv DIT step (select form, init/snapshot paths only)
    auto inv_s = [&](float2& zz, float bx, float by, int s, bool hi) {
        const float px = hi ? zz.x : bx, py = hi ? zz.y : by;
        const float qx = hi ? bx : zz.x, qy = hi ? by : zz.y;
        zz.x = qx + px * wi[s].x - py * wi[s].y;
        zz.y = qy + px * wi[s].y + py * wi[s].x;
    };

    // fwd lane chain h=32,16 (permlane) + 8,4,2 (DPP). h=1 handled by caller.
    auto lane_fwd5 = [&](float2 z[2]) {
        #pragma unroll
        for (int r = 0; r < 2; ++r) {
            float lox, hix, loy, hiy;
            pswap32(z[r].x, lox, hix); pswap32(z[r].y, loy, hiy);
            const float tx = fmaf(sg[0], hix, lox);   // lo + sg*hi
            const float ty = fmaf(sg[0], hiy, loy);
            z[r].x = tx * wf[0].x - ty * wf[0].y;
            z[r].y = tx * wf[0].y + ty * wf[0].x;
        }
        #pragma unroll
        for (int r = 0; r < 2; ++r) {
            float lox, hix, loy, hiy;
            pswap16(z[r].x, lox, hix); pswap16(z[r].y, loy, hiy);
            const float tx = fmaf(sg[1], hix, lox);
            const float ty = fmaf(sg[1], hiy, loy);
            z[r].x = tx * wf[1].x - ty * wf[1].y;
            z[r].y = tx * wf[1].y + ty * wf[1].x;
        }
        #pragma unroll
        for (int r = 0; r < 2; ++r) fwd_s(z[r], xr8(z[r].x), xr8(z[r].y), 2);
        #pragma unroll
        for (int r = 0; r < 2; ++r) fwd_s(z[r], xr4(z[r].x), xr4(z[r].y), 3);
        #pragma unroll
        for (int r = 0; r < 2; ++r) fwd_s(z[r], qx2(z[r].x), qx2(z[r].y), 4);
    };
    // inv lane chain h=2,4,8 (DPP select-free) + 16,32 (permlane). h=1 by caller.
    auto lane_inv5 = [&](float2 z[2]) {
        #pragma unroll
        for (int r = 0; r < 2; ++r) {
            const float px = qx2(z[r].x), py = qx2(z[r].y);
            const float nx = fmaf(cai[0].x, z[r].x, fmaf(-cai[0].y, z[r].y,
                             fmaf(cbi[0].x, px, -cbi[0].y * py)));
            const float ny = fmaf(cai[0].x, z[r].y, fmaf(cai[0].y, z[r].x,
                             fmaf(cbi[0].x, py, cbi[0].y * px)));
            z[r] = make_float2(nx, ny);
        }
        #pragma unroll
        for (int r = 0; r < 2; ++r) {
            const float px = xr4(z[r].x), py = xr4(z[r].y);
            const float nx = fmaf(cai[1].x, z[r].x, fmaf(-cai[1].y, z[r].y,
                             fmaf(cbi[1].x, px, -cbi[1].y * py)));
            const float ny = fmaf(cai[1].x, z[r].y, fmaf(cai[1].y, z[r].x,
                             fmaf(cbi[1].x, py, cbi[1].y * px)));
            z[r] = make_float2(nx, ny);
        }
        #pragma unroll
        for (int r = 0; r < 2; ++r) {
            const float px = xr8(z[r].x), py = xr8(z[r].y);
            const float nx = fmaf(cai[2].x, z[r].x, fmaf(-cai[2].y, z[r].y,
                             fmaf(cbi[2].x, px, -cbi[2].y * py)));
            const float ny = fmaf(cai[2].x, z[r].y, fmaf(cai[2].y, z[r].x,
                             fmaf(cbi[2].x, py, cbi[2].y * px)));
            z[r] = make_float2(nx, ny);
        }
        #pragma unroll
        for (int r = 0; r < 2; ++r) {
            float lox, hix, loy, hiy;
            pswap16(z[r].x, lox, hix); pswap16(z[r].y, loy, hiy);
            z[r].x = fmaf(wi[4].x, hix, fmaf(-wi[4].y, hiy, lox));
            z[r].y = fmaf(wi[4].x, hiy, fmaf( wi[4].y, hix, loy));
        }
        #pragma unroll
        for (int r = 0; r < 2; ++r) {
            float lox, hix, loy, hiy;
            pswap32(z[r].x, lox, hix); pswap32(z[r].y, loy, hiy);
            z[r].x = fmaf(wi[5].x, hix, fmaf(-wi[5].y, hiy, lox));
            z[r].y = fmaf(wi[5].x, hiy, fmaf( wi[5].y, hix, loy));
        }
    };

    // fwd head: radix-2 reg digit -> LDS write -> factored radix-8 gather -> lane 5 stages
    auto fwd_head = [&](float2 z[2]) {
        const float2 A  = make_float2(z[0].x + z[1].x, z[0].y + z[1].y);
        const float2 Dm = make_float2(z[0].x - z[1].x, z[0].y - z[1].y);
        const float2 Bc = make_float2(Dm.x * T10.x - Dm.y * T10.y,
                                      Dm.x * T10.y + Dm.y * T10.x);
        bufF[tt] = make_float4(A.x, A.y, Bc.x, Bc.y);
        __syncthreads();
        // pairs (j, j+4): a_i = v[j] + pm*v[j+4]  (A parts .x.y, B parts .z.w)
        float a0x, a0y, a0z, a0w, a1x, a1y, a1z, a1w;
        float a2x, a2y, a2z, a2w, a3x, a3y, a3z, a3w;
        {
            const float4 u0 = bufF[l],        u4 = bufF[256 + l];
            a0x = fmaf(pm, u4.x, u0.x);  a0y = fmaf(pm, u4.y, u0.y);
            a0z = fmaf(pm, u4.z, u0.z);  a0w = fmaf(pm, u4.w, u0.w);
        }
        {
            const float4 u2 = bufF[128 + l],  u6 = bufF[384 + l];
            a1x = fmaf(pm, u6.x, u2.x);  a1y = fmaf(pm, u6.y, u2.y);
            a1z = fmaf(pm, u6.z, u2.z);  a1w = fmaf(pm, u6.w, u2.w);
        }
        {
            const float4 u1 = bufF[64 + l],   u5 = bufF[320 + l];
            a2x = fmaf(pm, u5.x, u1.x);  a2y = fmaf(pm, u5.y, u1.y);
            a2z = fmaf(pm, u5.z, u1.z);  a2w = fmaf(pm, u5.w, u1.w);
        }
        {
            const float4 u3 = bufF[192 + l],  u7 = bufF[448 + l];
            a3x = fmaf(pm, u7.x, u3.x);  a3y = fmaf(pm, u7.y, u3.y);
            a3z = fmaf(pm, u7.z, u3.z);  a3w = fmaf(pm, u7.w, u3.w);
        }
        // A sequence
        {
            const float Ex = fmaf(c4w.x, a1x, fmaf(-c4w.y, a1y, a0x));
            const float Ey = fmaf(c4w.x, a1y, fmaf( c4w.y, a1x, a0y));
            const float Fx = fmaf(c4w.x, a3x, fmaf(-c4w.y, a3y, a2x));
            const float Fy = fmaf(c4w.x, a3y, fmaf( c4w.y, a3x, a2y));
            const float Sx = fmaf(w8w.x, Fx, fmaf(-w8w.y, Fy, Ex));
            const float Sy = fmaf(w8w.x, Fy, fmaf( w8w.y, Fx, Ey));
            z[0] = make_float2(Sx * rotf.x - Sy * rotf.y,
                               Sx * rotf.y + Sy * rotf.x);
        }
        // B sequence
        {
            const float Ex = fmaf(c4w.x, a1z, fmaf(-c4w.y, a1w, a0z));
            const float Ey = fmaf(c4w.x, a1w, fmaf( c4w.y, a1z, a0w));
            const float Fx = fmaf(c4w.x, a3z, fmaf(-c4w.y, a3w, a2z));
            const float Fy = fmaf(c4w.x, a3w, fmaf( c4w.y, a3z, a2w));
            const float Sx = fmaf(w8w.x, Fx, fmaf(-w8w.y, Fy, Ex));
            const float Sy = fmaf(w8w.x, Fy, fmaf( w8w.y, Fx, Ey));
            z[1] = make_float2(Sx * rotf.x - Sy * rotf.y,
                               Sx * rotf.y + Sy * rotf.x);
        }
        lane_fwd5(z);
    };

    // inv tail: lane 5 stages -> LDS write -> inverse gather (j=0 skipped)
    auto inv_tail = [&](float2 z[2], float& u0o, float& u1o) {
        lane_inv5(z);
        bufI[tt] = make_float4(z[0].x, z[0].y, z[1].x, z[1].y);
        __syncthreads();
        float vAx, vBx, vBy;
        { const float4 v0 = bufI[l];
          vAx = v0.x; vBx = v0.z; vBy = v0.w; }
        #pragma unroll
        for (int j = 1; j < 8; ++j) {
            const float4 v = bufI[64 * j + l];
            vAx = fmaf(D8[j].x, v.x, vAx);  vAx = fmaf(-D8[j].y, v.y, vAx);
            vBx = fmaf(D8[j].x, v.z, vBx);  vBx = fmaf(-D8[j].y, v.w, vBx);
            vBy = fmaf(D8[j].x, v.w, vBy);  vBy = fmaf(D8[j].y, v.z, vBy);
        }
        const float re = vBx * T10.x + vBy * T10.y;   // Re(vB * conj(T10))
        u0o = vAx + re;
        u1o = vAx - re;
    };

    // ---- init: d_to_u (full unfused fwd + pointwise + full unfused inv) ----
    float2 z[2];
    float u0, u1;
    z[0] = make_float2(x[b * NFFT + tt], 0.0f);
    z[1] = make_float2(x[b * NFFT + tt + 512], 0.0f);
    fwd_head(z);
    #pragma unroll
    for (int r = 0; r < 2; ++r) fwd_s(z[r], qx1(z[r].x), qx1(z[r].y), 5);  // h=1
    #pragma unroll
    for (int p = 0; p < 2; ++p) {
        const float zx = z[p].x, zy = z[p].y;
        z[p] = make_float2(-zy * si[p], zx * si[p]);   // i*k*Z / N
    }
    #pragma unroll
    for (int r = 0; r < 2; ++r) inv_s(z[r], qx1(z[r].x), qx1(z[r].y), 0, m1);
    inv_tail(z, u0, u1);

    for (int ot = 0; ot < nT; ++ot) {
        for (int ss = 0; ss < nsub; ++ss) {
            z[0] = make_float2(u0, 0.5f * u0 * u0);
            z[1] = make_float2(u1, 0.5f * u1 * u1);
            fwd_head(z);
            // fused: fwd h=1 + S scale + inv h=1 (real coefficients)
            #pragma unroll
            for (int p = 0; p < 2; ++p) {
                const float px = qx1(z[p].x), py = qx1(z[p].y);
                z[p].x = fmaf(A2[p], z[p].x, B2[p] * px);
                z[p].y = fmaf(A2[p], z[p].y, B2[p] * py);
            }
            inv_tail(z, u0, u1);
        }
        // snapshot: u_to_d (unfused)
        z[0] = make_float2(u0, 0.0f);
        z[1] = make_float2(u1, 0.0f);
        fwd_head(z);
        #pragma unroll
        for (int r = 0; r < 2; ++r) fwd_s(z[r], qx1(z[r].x), qx1(z[r].y), 5);
        #pragma unroll
        for (int p = 0; p < 2; ++p) {
            const float zx = z[p].x, zy = z[p].y;
            z[p] = make_float2(zy * csn[p], -zx * csn[p]);  // -i*Z/(N*k)
        }
        #pragma unroll
        for (int r = 0; r < 2; ++r) inv_s(z[r], qx1(z[r].x), qx1(z[r].y), 0, m1);
        float d0, d1;
        inv_tail(z, d0, d1);
        out[(b * NFFT + tt) * nT + ot]       = d0;
        out[(b * NFFT + tt + 512) * nT + ot] = d1;
    }
}

extern "C" void kernel_launch(void* const* d_in, const int* in_sizes, int n_in,
                              void* d_out, int out_size, void* d_ws, size_t ws_size,
                              hipStream_t stream) {
    const float* x     = (const float*)d_in[0];
    const float* nu_p  = (const float*)d_in[1];
    const float* dto_p = (const float*)d_in[2];
    const float* cr_p  = (const float*)d_in[3];
    const int*   nt_p  = (const int*)d_in[4];
    const int*   ns_p  = (const int*)d_in[5];
    float* out = (float*)d_out;

    const int B = in_sizes[0] / NFFT;  // C == 1
    siva_kernel<<<B, BLK, 0, stream>>>(x, nu_p, dto_p, cr_p, nt_p, ns_p, out);
}